// Round 4
// baseline (268.492 us; speedup 1.0000x reference)
//
#include <hip/hip_runtime.h>
#include <math.h>

#define N_NODES 10000
#define N_EDGES 160000
#define CAP 64      // bucket capacity per node (Poisson(16), P(deg>64) ~ 1e-19)
#define NBLK 512    // main-kernel grid; co-resident by construction (2 blocks/CU)

// R12: 2-dispatch chain (was 4-5).
// Evidence: theoretical kernel work is ~30us but windows measure 103-117us
// across wildly different structures; R6->R9 (6->5 dispatches) saved 14us.
// => per-dispatch overhead dominates. Fold the 4 dependent phases into ONE
// kernel with hand-rolled device-wide barriers (arrive: 1 agent-scope atomic
// per block; spin: acquire-load). NOT cooperative grid.sync (measured 25us/sync
// in a prior session). Safety: 512 blocks x 512 thr, __launch_bounds__(512,4)
// -> needs 2 blocks/CU, 4 possible -> all blocks co-resident, spin cannot
// deadlock. R10/R11's atomic-scatter pass-1 is reverted (cost +12us): pass-1
// is a bucket gather again.
//   D0 (k0):  zero cnt + zero bar[] + u,v partials     (u=W1@W2, v=b1@W2)
//   D1 (mega):
//     phase A: bucket fill (blocks 0..312) + p,q,r partials (313..328)
//     --gbar-- phase B: pass1 gather -> sd=(s1,deg)
//     --gbar-- phase C: pass2 gather -> t2, Bf; p,q,r final (block 400)
//     --gbar-- phase D: A-pass gather + 10000x512 expansion + sigmoid
//
// Workspace layout (floats):
//   [0       .. 10000)    cnt (int)        per-node slot counters
//   [10240   .. 10256)    bar (int[16])    barrier counters
//   [10752   .. 30752)    sd  float2(s1,deg)
//   [30752   .. 40752)    t2
//   [40752   .. 50752)    Bf
//   [50752   .. 51264)    p
//   [51264   .. 51776)    q
//   [51776   .. 52288)    r
//   [52288   .. 56384)    u_part[16][256]
//   [56384   .. 60480)    v_part[16][256]
//   [60480   .. 68672)    p_part[16][512]
//   [68672   .. 76864)    q_part[16][512]
//   [76864   .. 85056)    r_part[16][512]
//   [85056   .. 1365056)  bucket[10000][64] float2(src_bits, ew)

// Device-wide barrier: one dedicated counter per use (no sense reversal).
// Release on arrive pushes this block's stores device-visible; acquire on the
// spin load invalidates stale L1/L2 lines before the next phase reads.
__device__ inline void gbar(int* bar) {
    __syncthreads();
    if (threadIdx.x == 0) {
        __hip_atomic_fetch_add(bar, 1, __ATOMIC_RELEASE, __HIP_MEMORY_SCOPE_AGENT);
        while (__hip_atomic_load(bar, __ATOMIC_ACQUIRE, __HIP_MEMORY_SCOPE_AGENT) < NBLK) {
            __builtin_amdgcn_s_sleep(2);
        }
    }
    __syncthreads();
}

// ---------- D0: zero cnt + bars + u/v partials -----------------------------
__global__ __launch_bounds__(512) void k0_kernel(
        int* __restrict__ cnt, int* __restrict__ bar,
        const float* __restrict__ W1, const float* __restrict__ b1,
        const float* __restrict__ W2,
        float* __restrict__ u_part, float* __restrict__ v_part) {
    int tid = threadIdx.x;
    int blk = blockIdx.x;
    if (blk == 0) {
        for (int g = tid; g < N_NODES / 4; g += 512)
            ((int4*)cnt)[g] = make_int4(0, 0, 0, 0);
        if (tid < 16) bar[tid] = 0;
    } else {
        int b = blk - 1;                 // 0..15, j-chunk [8b, 8b+8)
        if (tid < 256) {
            int j0 = b * 8;
            float uu = 0.f, vv = 0.f;
            #pragma unroll
            for (int jj = 0; jj < 8; ++jj) {
                float w2 = W2[(j0 + jj) * 256 + tid];   // coalesced
                uu = fmaf(W1[j0 + jj], w2, uu);
                vv = fmaf(b1[j0 + jj], w2, vv);
            }
            u_part[b * 256 + tid] = uu;
            v_part[b * 256 + tid] = vv;
        }
    }
}

// ---------- D1: mega-kernel (4 phases, 3 device barriers) ------------------
__global__ __launch_bounds__(512, 4) void mega_kernel(
        const int* __restrict__ src, const int* __restrict__ dst,
        const float* __restrict__ ew, const float* __restrict__ x,
        int* __restrict__ cnt, int* __restrict__ bar,
        float2* __restrict__ bucket, float2* __restrict__ sd,
        float* __restrict__ t2, float* __restrict__ Bf,
        const float* __restrict__ u_part, const float* __restrict__ v_part,
        const float* __restrict__ b2, const float* __restrict__ W3,
        float* __restrict__ p_part, float* __restrict__ q_part,
        float* __restrict__ r_part,
        float* __restrict__ p, float* __restrict__ q, float* __restrict__ r,
        const float* __restrict__ b3, float* __restrict__ out) {
    int tid = threadIdx.x;
    int blk = blockIdx.x;
    __shared__ float su[16], sv[16], sb[16];
    __shared__ float A_l[16], B_l[16], D_l[16];

    // ---- phase A: bucket fill + pqr partials ----
    if (blk < 313) {
        int e = blk * 512 + tid;
        if (e < N_EDGES) {
            int   s = src[e];
            int   d = dst[e];
            float w = ew[e];
            int slot = atomicAdd(&cnt[d], 1);
            if (slot < CAP)
                bucket[d * CAP + slot] = make_float2(__int_as_float(s), w);
        }
    } else if (blk < 329) {
        int c = blk - 313;               // 0..15, k-chunk [16c,16c+16)
        if (tid < 16) {
            int kk = c * 16 + tid;
            float uu = 0.f, vv = 0.f;
            #pragma unroll
            for (int b = 0; b < 16; ++b) {
                uu += u_part[b * 256 + kk];
                vv += v_part[b * 256 + kk];
            }
            su[tid] = uu; sv[tid] = vv; sb[tid] = b2[kk];
        }
        __syncthreads();
        float pp = 0.f, qq = 0.f, rr = 0.f;
        #pragma unroll
        for (int kk = 0; kk < 16; ++kk) {
            float w3 = W3[(c * 16 + kk) * 512 + tid];   // coalesced
            pp = fmaf(su[kk], w3, pp);
            qq = fmaf(sv[kk], w3, qq);
            rr = fmaf(sb[kk], w3, rr);
        }
        p_part[c * 512 + tid] = pp;
        q_part[c * 512 + tid] = qq;
        r_part[c * 512 + tid] = rr;
    }
    gbar(&bar[0]);

    // ---- phase B: pass1 gather -> sd ----
    if (blk < 313) {
        int gid = blk * 512 + tid;
        int n = gid >> 4;                // node
        int l = gid & 15;                // lane within node group
        if (n < N_NODES) {
            int c = cnt[n]; if (c > CAP) c = CAP;
            float s1 = 0.f, dg = 0.f;
            for (int i = l; i < c; i += 16) {
                float2 e = bucket[n * CAP + i];      // 128B/node, coalesced
                s1 = fmaf(e.y, x[__float_as_int(e.x)], s1);
                dg += e.y;
            }
            #pragma unroll
            for (int m = 1; m < 16; m <<= 1) {
                s1 += __shfl_xor(s1, m);
                dg += __shfl_xor(dg, m);
            }
            if (l == 0) sd[n] = make_float2(s1, dg);
        }
    }
    gbar(&bar[1]);

    // ---- phase C: pass2 gather -> t2, Bf; pqr final ----
    if (blk < 313) {
        int gid = blk * 512 + tid;
        int n = gid >> 4;
        int l = gid & 15;
        if (n < N_NODES) {
            int c = cnt[n]; if (c > CAP) c = CAP;
            float tt = 0.f, bb = 0.f;
            for (int i = l; i < c; i += 16) {
                float2 e = bucket[n * CAP + i];
                float2 v = sd[__float_as_int(e.x)];  // gather (s1, deg)
                tt = fmaf(e.y, v.x, tt);
                bb = fmaf(e.y, v.y, bb);
            }
            #pragma unroll
            for (int m = 1; m < 16; m <<= 1) {
                tt += __shfl_xor(tt, m);
                bb += __shfl_xor(bb, m);
            }
            if (l == 0) { t2[n] = tt; Bf[n] = bb; }
        }
    } else if (blk == 400) {
        float pp = 0.f, qq = 0.f, rr = 0.f;
        #pragma unroll
        for (int c2 = 0; c2 < 16; ++c2) {
            pp += p_part[c2 * 512 + tid];
            qq += q_part[c2 * 512 + tid];
            rr += r_part[c2 * 512 + tid];
        }
        p[tid] = pp; q[tid] = qq; r[tid] = rr;
    }
    gbar(&bar[2]);

    // ---- phase D: A-pass + expansion + sigmoid ----
    for (int t = blk; t < 625; t += NBLK) {
        int n0 = t * 16;
        if (tid < 256) {
            int nl = tid >> 4;           // local node 0..15
            int l = tid & 15;            // lane within node group
            int n = n0 + nl;
            int c = cnt[n]; if (c > CAP) c = CAP;
            float acc = 0.f;
            for (int i = l; i < c; i += 16) {
                float2 e = bucket[n * CAP + i];
                acc = fmaf(e.y, t2[__float_as_int(e.x)], acc);
            }
            #pragma unroll
            for (int m = 1; m < 16; m <<= 1) acc += __shfl_xor(acc, m);
            if (l == 0) {
                A_l[nl] = acc;
                B_l[nl] = Bf[n];
                D_l[nl] = sd[n].y;       // deg
            }
        }
        __syncthreads();
        #pragma unroll
        for (int h = 0; h < 4; ++h) {
            int idx = h * 512 + tid;     // 0..2047 within tile
            int nl = idx >> 7;           // local node 0..15
            int j = idx & 127;           // float4 column
            float a = A_l[nl], b = B_l[nl], dg = D_l[nl];
            float4 P = ((const float4*)p)[j];
            float4 Q = ((const float4*)q)[j];
            float4 R = ((const float4*)r)[j];
            float4 B3 = ((const float4*)b3)[j];
            float4 o;
            float zx = fmaf(a, P.x, fmaf(b, Q.x, fmaf(dg, R.x, B3.x)));
            float zy = fmaf(a, P.y, fmaf(b, Q.y, fmaf(dg, R.y, B3.y)));
            float zz = fmaf(a, P.z, fmaf(b, Q.z, fmaf(dg, R.z, B3.z)));
            float zw = fmaf(a, P.w, fmaf(b, Q.w, fmaf(dg, R.w, B3.w)));
            o.x = 1.f / (1.f + __expf(-zx));
            o.y = 1.f / (1.f + __expf(-zy));
            o.z = 1.f / (1.f + __expf(-zz));
            o.w = 1.f / (1.f + __expf(-zw));
            ((float4*)out)[(size_t)(n0 + nl) * 128 + j] = o;
        }
        __syncthreads();
    }
}

extern "C" void kernel_launch(void* const* d_in, const int* in_sizes, int n_in,
                              void* d_out, int out_size, void* d_ws, size_t ws_size,
                              hipStream_t stream) {
    const float* x  = (const float*)d_in[0];
    const int*   ei = (const int*)d_in[1];
    const float* ew = (const float*)d_in[2];
    const float* W1 = (const float*)d_in[3];
    const float* b1 = (const float*)d_in[4];
    const float* W2 = (const float*)d_in[5];
    const float* b2 = (const float*)d_in[6];
    const float* W3 = (const float*)d_in[7];
    const float* b3 = (const float*)d_in[8];
    float* out = (float*)d_out;

    float* ws       = (float*)d_ws;
    int*    cnt     = (int*)ws;                    // 10000 ints
    int*    bar     = (int*)(ws + 10240);          // 16 ints
    float2* sd      = (float2*)(ws + 10752);
    float*  t2      = ws + 30752;
    float*  Bf      = ws + 40752;
    float*  p       = ws + 50752;
    float*  q       = ws + 51264;
    float*  r       = ws + 51776;
    float*  u_part  = ws + 52288;
    float*  v_part  = ws + 56384;
    float*  p_part  = ws + 60480;
    float*  q_part  = ws + 68672;
    float*  r_part  = ws + 76864;
    float2* bucket  = (float2*)(ws + 85056);       // 10000 x 64 float2

    const int* src = ei;            // edge_index[0]
    const int* dst = ei + N_EDGES;  // edge_index[1]

    k0_kernel<<<17, 512, 0, stream>>>(cnt, bar, W1, b1, W2, u_part, v_part);
    mega_kernel<<<NBLK, 512, 0, stream>>>(src, dst, ew, x, cnt, bar,
                                          bucket, sd, t2, Bf,
                                          u_part, v_part, b2, W3,
                                          p_part, q_part, r_part, p, q, r,
                                          b3, out);
}

// Round 5
// 159.479 us; speedup vs baseline: 1.6836x; 1.6836x over previous
//
#include <hip/hip_runtime.h>
#include <math.h>

#define N_NODES 10000
#define N_EDGES 160000
#define CAP 64      // bucket capacity per node (Poisson(16), P(deg>64) ~ 1e-19)
#define NBLK 336    // main-kernel grid; co-resident by construction (2 blocks/CU)

// R13: 2-dispatch chain with a FIXED device-wide barrier.
// R12 post-mortem: mega=202us with 2% HBM / 1.7% VALU -> barriers cost ~55us
// each. Cause: agent-scope ACQUIRE load in the spin loop => one buffer_inv
// (chip-global cache-maintenance) per poll per block = invalidate storm that
// serializes at the TCC. Fix: RELAXED polls with s_sleep backoff; exactly one
// RELEASE (on arrive) and one ACQUIRE fence (on exit) per block per barrier.
// R12 also settled the window arithmetic: the 268MB workspace re-poison fill
// (~42us) is INSIDE the timed window (fixed cost), boundaries ~5-10us each.
//   D0 (k0):  zero cnt + bar[] only (~2us)
//   D1 (mega):
//     phase A: bucket fill (blocks 0..312) + u,v partials (313..328)
//     --gbar-- phase B: pass1 gather -> sd=(s1,deg) + p,q,r partials
//     --gbar-- phase C: pass2 gather -> t2, Bf; p,q,r final (block 329)
//     --gbar-- phase D: A-pass gather + 10000x512 expansion + sigmoid
//
// Workspace layout (floats):
//   [0       .. 10000)    cnt (int)        per-node slot counters
//   [10240   .. 10256)    bar (int[16])    barrier counters
//   [10752   .. 30752)    sd  float2(s1,deg)
//   [30752   .. 40752)    t2
//   [40752   .. 50752)    Bf
//   [50752   .. 51264)    p
//   [51264   .. 51776)    q
//   [51776   .. 52288)    r
//   [52288   .. 56384)    u_part[16][256]
//   [56384   .. 60480)    v_part[16][256]
//   [60480   .. 68672)    p_part[16][512]
//   [68672   .. 76864)    q_part[16][512]
//   [76864   .. 85056)    r_part[16][512]
//   [85056   .. 1365056)  bucket[10000][64] float2(src_bits, ew)

// Device-wide barrier, cache-op-minimal:
//   arrive: ONE agent-scope RELEASE fetch_add (emits one L2 writeback --
//           required so this block's plain stores become cross-XCD visible)
//   spin:   RELAXED loads + s_sleep backoff (NO cache maintenance per poll)
//   exit:   ONE agent-scope ACQUIRE fence (one invalidate, so subsequent
//           reads see remote XCDs' writes)
__device__ inline void gbar(int* bar) {
    __syncthreads();
    if (threadIdx.x == 0) {
        __hip_atomic_fetch_add(bar, 1, __ATOMIC_RELEASE, __HIP_MEMORY_SCOPE_AGENT);
        while (__hip_atomic_load(bar, __ATOMIC_RELAXED, __HIP_MEMORY_SCOPE_AGENT) < NBLK)
            __builtin_amdgcn_s_sleep(8);
        __builtin_amdgcn_fence(__ATOMIC_ACQUIRE, "agent");
    }
    __syncthreads();
}

// ---------- D0: zero cnt + bar only ----------------------------------------
__global__ __launch_bounds__(512) void k0_kernel(
        int* __restrict__ cnt, int* __restrict__ bar) {
    int tid = threadIdx.x;
    int blk = blockIdx.x;
    if (blk < 8) {
        // cnt: 2500 int4 total, 313 per block (lockstep over 8 blocks)
        int4* c4 = (int4*)cnt;
        for (int g = blk * 313 + tid; g < (blk + 1) * 313 && g < 2500; g += 512)
            c4[g] = make_int4(0, 0, 0, 0);
    } else {
        if (tid < 16) bar[tid] = 0;
    }
}

// ---------- D1: mega-kernel (4 phases, 3 device barriers) ------------------
__global__ __launch_bounds__(512, 4) void mega_kernel(
        const int* __restrict__ src, const int* __restrict__ dst,
        const float* __restrict__ ew, const float* __restrict__ x,
        int* __restrict__ cnt, int* __restrict__ bar,
        float2* __restrict__ bucket, float2* __restrict__ sd,
        float* __restrict__ t2, float* __restrict__ Bf,
        const float* __restrict__ W1, const float* __restrict__ b1,
        const float* __restrict__ W2,
        float* __restrict__ u_part, float* __restrict__ v_part,
        const float* __restrict__ b2, const float* __restrict__ W3,
        float* __restrict__ p_part, float* __restrict__ q_part,
        float* __restrict__ r_part,
        float* __restrict__ p, float* __restrict__ q, float* __restrict__ r,
        const float* __restrict__ b3, float* __restrict__ out) {
    int tid = threadIdx.x;
    int blk = blockIdx.x;
    __shared__ float su[16], sv[16], sb[16];
    __shared__ float A_l[16], B_l[16], D_l[16];

    // ---- phase A: bucket fill + u/v partials ----
    if (blk < 313) {
        int e = blk * 512 + tid;
        if (e < N_EDGES) {
            int   s = src[e];
            int   d = dst[e];
            float w = ew[e];
            int slot = atomicAdd(&cnt[d], 1);
            if (slot < CAP)
                bucket[d * CAP + slot] = make_float2(__int_as_float(s), w);
        }
    } else if (blk < 329) {
        int b = blk - 313;               // 0..15, j-chunk [8b, 8b+8)
        if (tid < 256) {
            int j0 = b * 8;
            float uu = 0.f, vv = 0.f;
            #pragma unroll
            for (int jj = 0; jj < 8; ++jj) {
                float w2 = W2[(j0 + jj) * 256 + tid];   // coalesced
                uu = fmaf(W1[j0 + jj], w2, uu);
                vv = fmaf(b1[j0 + jj], w2, vv);
            }
            u_part[b * 256 + tid] = uu;
            v_part[b * 256 + tid] = vv;
        }
    }
    gbar(&bar[0]);

    // ---- phase B: pass1 gather -> sd; pqr partials ----
    if (blk < 313) {
        int gid = blk * 512 + tid;
        int n = gid >> 4;                // node
        int l = gid & 15;                // lane within node group
        if (n < N_NODES) {
            int c = cnt[n]; if (c > CAP) c = CAP;
            float s1 = 0.f, dg = 0.f;
            for (int i = l; i < c; i += 16) {
                float2 e = bucket[n * CAP + i];      // 128B/node, coalesced
                s1 = fmaf(e.y, x[__float_as_int(e.x)], s1);
                dg += e.y;
            }
            #pragma unroll
            for (int m = 1; m < 16; m <<= 1) {
                s1 += __shfl_xor(s1, m);
                dg += __shfl_xor(dg, m);
            }
            if (l == 0) sd[n] = make_float2(s1, dg);
        }
    } else if (blk < 329) {
        int c = blk - 313;               // 0..15, k-chunk [16c,16c+16)
        if (tid < 16) {
            int kk = c * 16 + tid;
            float uu = 0.f, vv = 0.f;
            #pragma unroll
            for (int b = 0; b < 16; ++b) {
                uu += u_part[b * 256 + kk];
                vv += v_part[b * 256 + kk];
            }
            su[tid] = uu; sv[tid] = vv; sb[tid] = b2[kk];
        }
        __syncthreads();
        float pp = 0.f, qq = 0.f, rr = 0.f;
        #pragma unroll
        for (int kk = 0; kk < 16; ++kk) {
            float w3 = W3[(c * 16 + kk) * 512 + tid];   // coalesced
            pp = fmaf(su[kk], w3, pp);
            qq = fmaf(sv[kk], w3, qq);
            rr = fmaf(sb[kk], w3, rr);
        }
        p_part[c * 512 + tid] = pp;
        q_part[c * 512 + tid] = qq;
        r_part[c * 512 + tid] = rr;
    }
    gbar(&bar[1]);

    // ---- phase C: pass2 gather -> t2, Bf; pqr final ----
    if (blk < 313) {
        int gid = blk * 512 + tid;
        int n = gid >> 4;
        int l = gid & 15;
        if (n < N_NODES) {
            int c = cnt[n]; if (c > CAP) c = CAP;
            float tt = 0.f, bb = 0.f;
            for (int i = l; i < c; i += 16) {
                float2 e = bucket[n * CAP + i];
                float2 v = sd[__float_as_int(e.x)];  // gather (s1, deg)
                tt = fmaf(e.y, v.x, tt);
                bb = fmaf(e.y, v.y, bb);
            }
            #pragma unroll
            for (int m = 1; m < 16; m <<= 1) {
                tt += __shfl_xor(tt, m);
                bb += __shfl_xor(bb, m);
            }
            if (l == 0) { t2[n] = tt; Bf[n] = bb; }
        }
    } else if (blk == 329) {
        float pp = 0.f, qq = 0.f, rr = 0.f;
        #pragma unroll
        for (int c2 = 0; c2 < 16; ++c2) {
            pp += p_part[c2 * 512 + tid];
            qq += q_part[c2 * 512 + tid];
            rr += r_part[c2 * 512 + tid];
        }
        p[tid] = pp; q[tid] = qq; r[tid] = rr;
    }
    gbar(&bar[2]);

    // ---- phase D: A-pass + expansion + sigmoid ----
    for (int t = blk; t < 625; t += NBLK) {
        int n0 = t * 16;
        if (tid < 256) {
            int nl = tid >> 4;           // local node 0..15
            int l = tid & 15;            // lane within node group
            int n = n0 + nl;
            int c = cnt[n]; if (c > CAP) c = CAP;
            float acc = 0.f;
            for (int i = l; i < c; i += 16) {
                float2 e = bucket[n * CAP + i];
                acc = fmaf(e.y, t2[__float_as_int(e.x)], acc);
            }
            #pragma unroll
            for (int m = 1; m < 16; m <<= 1) acc += __shfl_xor(acc, m);
            if (l == 0) {
                A_l[nl] = acc;
                B_l[nl] = Bf[n];
                D_l[nl] = sd[n].y;       // deg
            }
        }
        __syncthreads();
        #pragma unroll
        for (int h = 0; h < 4; ++h) {
            int idx = h * 512 + tid;     // 0..2047 within tile
            int nl = idx >> 7;           // local node 0..15
            int j = idx & 127;           // float4 column
            float a = A_l[nl], b = B_l[nl], dg = D_l[nl];
            float4 P = ((const float4*)p)[j];
            float4 Q = ((const float4*)q)[j];
            float4 R = ((const float4*)r)[j];
            float4 B3 = ((const float4*)b3)[j];
            float4 o;
            float zx = fmaf(a, P.x, fmaf(b, Q.x, fmaf(dg, R.x, B3.x)));
            float zy = fmaf(a, P.y, fmaf(b, Q.y, fmaf(dg, R.y, B3.y)));
            float zz = fmaf(a, P.z, fmaf(b, Q.z, fmaf(dg, R.z, B3.z)));
            float zw = fmaf(a, P.w, fmaf(b, Q.w, fmaf(dg, R.w, B3.w)));
            o.x = 1.f / (1.f + __expf(-zx));
            o.y = 1.f / (1.f + __expf(-zy));
            o.z = 1.f / (1.f + __expf(-zz));
            o.w = 1.f / (1.f + __expf(-zw));
            ((float4*)out)[(size_t)(n0 + nl) * 128 + j] = o;
        }
        __syncthreads();
    }
}

extern "C" void kernel_launch(void* const* d_in, const int* in_sizes, int n_in,
                              void* d_out, int out_size, void* d_ws, size_t ws_size,
                              hipStream_t stream) {
    const float* x  = (const float*)d_in[0];
    const int*   ei = (const int*)d_in[1];
    const float* ew = (const float*)d_in[2];
    const float* W1 = (const float*)d_in[3];
    const float* b1 = (const float*)d_in[4];
    const float* W2 = (const float*)d_in[5];
    const float* b2 = (const float*)d_in[6];
    const float* W3 = (const float*)d_in[7];
    const float* b3 = (const float*)d_in[8];
    float* out = (float*)d_out;

    float* ws       = (float*)d_ws;
    int*    cnt     = (int*)ws;                    // 10000 ints
    int*    bar     = (int*)(ws + 10240);          // 16 ints
    float2* sd      = (float2*)(ws + 10752);
    float*  t2      = ws + 30752;
    float*  Bf      = ws + 40752;
    float*  p       = ws + 50752;
    float*  q       = ws + 51264;
    float*  r       = ws + 51776;
    float*  u_part  = ws + 52288;
    float*  v_part  = ws + 56384;
    float*  p_part  = ws + 60480;
    float*  q_part  = ws + 68672;
    float*  r_part  = ws + 76864;
    float2* bucket  = (float2*)(ws + 85056);       // 10000 x 64 float2

    const int* src = ei;            // edge_index[0]
    const int* dst = ei + N_EDGES;  // edge_index[1]

    k0_kernel<<<9, 512, 0, stream>>>(cnt, bar);
    mega_kernel<<<NBLK, 512, 0, stream>>>(src, dst, ew, x, cnt, bar,
                                          bucket, sd, t2, Bf,
                                          W1, b1, W2, u_part, v_part,
                                          b2, W3, p_part, q_part, r_part,
                                          p, q, r, b3, out);
}

// Round 6
// 133.507 us; speedup vs baseline: 2.0111x; 1.1945x over previous
//
#include <hip/hip_runtime.h>
#include <math.h>

#define N_NODES 10000
#define N_EDGES 160000
#define CAP 64      // bucket capacity per node (Poisson(16), P(deg>64) ~ 1e-19)
#define NBLK 330    // main-kernel grid; co-resident by construction (2 blocks/CU)

// R14: 2-dispatch, FENCE-FREE device barrier via write-through data.
// R13 post-mortem: barriers still ~19us each. The cost is the per-block cache
// maintenance: acquire = buffer_inv (drops whole local L1/L2 -> phases run
// cold-cache), release = buffer_wbl2 (writes back dirty bucket lines). Fix:
// make cache maintenance unnecessary. ALL cross-phase produced data moves via
// relaxed agent-scope atomic loads/stores: stores are write-through to the
// coherence point (nothing dirty to flush), loads read the coherence point
// (nothing stale to invalidate). Read-only inputs keep normal cached loads and
// now STAY HOT across phases. Barrier = syncthreads (per-wave vmcnt drain =>
// write-through stores ack'd) + relaxed fetch_add + relaxed poll + syncthreads.
// Zero buffer_inv / buffer_wbl2 anywhere.
//   D0 (k0):  zero cnt + bar[] (~2us)
//   D1 (mega):
//     phase A: bucket fill (blocks 0..312) + u,v partials (313..328)
//     --gbar-- phase B: pass1 gather -> sd=(s1,deg) + p,q,r partials
//     --gbar-- phase C: pass2 gather -> t2, Bf; p,q,r final (block 329)
//     --gbar-- phase D: A-pass gather + 10000x512 expansion + sigmoid
//
// Workspace layout (floats):
//   [0       .. 10000)    cnt (int)        per-node slot counters
//   [10240   .. 10256)    bar (int[16])    barrier counters
//   [10752   .. 30752)    sd  float2(s1,deg)
//   [30752   .. 40752)    t2
//   [40752   .. 50752)    Bf
//   [50752   .. 51264)    p
//   [51264   .. 51776)    q
//   [51776   .. 52288)    r
//   [52288   .. 56384)    u_part[16][256]
//   [56384   .. 60480)    v_part[16][256]
//   [60480   .. 68672)    p_part[16][512]
//   [68672   .. 76864)    q_part[16][512]
//   [76864   .. 85056)    r_part[16][512]
//   [85056   .. 1365056)  bucket[10000][64] float2(src_bits, ew)

// ---- write-through (coherence-point) access helpers -----------------------
__device__ __forceinline__ float2 ld_f2(const float2* p) {
    unsigned long long v = __hip_atomic_load((unsigned long long*)p,
                               __ATOMIC_RELAXED, __HIP_MEMORY_SCOPE_AGENT);
    float2 r;
    r.x = __uint_as_float((unsigned)v);
    r.y = __uint_as_float((unsigned)(v >> 32));
    return r;
}
__device__ __forceinline__ void st_f2(float2* p, float x, float y) {
    unsigned long long v = ((unsigned long long)__float_as_uint(y) << 32)
                         | (unsigned long long)__float_as_uint(x);
    __hip_atomic_store((unsigned long long*)p, v,
                       __ATOMIC_RELAXED, __HIP_MEMORY_SCOPE_AGENT);
}
__device__ __forceinline__ float ld_f(const float* p) {
    return __hip_atomic_load((float*)p, __ATOMIC_RELAXED, __HIP_MEMORY_SCOPE_AGENT);
}
__device__ __forceinline__ void st_f(float* p, float v) {
    __hip_atomic_store(p, v, __ATOMIC_RELAXED, __HIP_MEMORY_SCOPE_AGENT);
}
__device__ __forceinline__ int ld_i(const int* p) {
    return __hip_atomic_load((int*)p, __ATOMIC_RELAXED, __HIP_MEMORY_SCOPE_AGENT);
}
__device__ __forceinline__ unsigned long long ld_u64(const unsigned long long* p) {
    return __hip_atomic_load((unsigned long long*)p,
                             __ATOMIC_RELAXED, __HIP_MEMORY_SCOPE_AGENT);
}

// Fence-free device-wide barrier. Preconditions: all cross-phase data was
// written with write-through atomic stores; __syncthreads drains each wave's
// vmcnt so those stores are ack'd at the coherence point before the arrive.
__device__ inline void gbar(int* bar) {
    __syncthreads();
    if (threadIdx.x == 0) {
        asm volatile("s_waitcnt vmcnt(0)" ::: "memory");   // belt-and-suspenders
        __hip_atomic_fetch_add(bar, 1, __ATOMIC_RELAXED, __HIP_MEMORY_SCOPE_AGENT);
        while (__hip_atomic_load(bar, __ATOMIC_RELAXED, __HIP_MEMORY_SCOPE_AGENT) < NBLK)
            __builtin_amdgcn_s_sleep(16);
    }
    __syncthreads();
}

// ---------- D0: zero cnt + bar ---------------------------------------------
__global__ __launch_bounds__(512) void k0_kernel(
        int* __restrict__ cnt, int* __restrict__ bar) {
    int tid = threadIdx.x;
    int blk = blockIdx.x;
    if (blk < 8) {
        int4* c4 = (int4*)cnt;
        for (int g = blk * 313 + tid; g < (blk + 1) * 313 && g < 2500; g += 512)
            c4[g] = make_int4(0, 0, 0, 0);
    } else {
        if (tid < 16) bar[tid] = 0;
    }
}

// ---------- D1: mega-kernel (4 phases, 3 fence-free barriers) --------------
__global__ __launch_bounds__(512, 4) void mega_kernel(
        const int* __restrict__ src, const int* __restrict__ dst,
        const float* __restrict__ ew, const float* __restrict__ x,
        int* __restrict__ cnt, int* __restrict__ bar,
        float2* __restrict__ bucket, float2* __restrict__ sd,
        float* __restrict__ t2, float* __restrict__ Bf,
        const float* __restrict__ W1, const float* __restrict__ b1,
        const float* __restrict__ W2,
        float* __restrict__ u_part, float* __restrict__ v_part,
        const float* __restrict__ b2, const float* __restrict__ W3,
        float* __restrict__ p_part, float* __restrict__ q_part,
        float* __restrict__ r_part,
        float* __restrict__ p, float* __restrict__ q, float* __restrict__ r,
        const float* __restrict__ b3, float* __restrict__ out) {
    int tid = threadIdx.x;
    int blk = blockIdx.x;
    __shared__ float su[16], sv[16], sb[16];
    __shared__ float A_l[16], B_l[16], D_l[16];
    __shared__ float sp[512], sq[512], sr[512];

    // ---- phase A: bucket fill + u/v partials ----
    if (blk < 313) {
        int e = blk * 512 + tid;
        if (e < N_EDGES) {
            int   s = src[e];                    // inputs: normal cached loads
            int   d = dst[e];
            float w = ew[e];
            int slot = atomicAdd(&cnt[d], 1);    // RMW at coherence point
            if (slot < CAP)
                st_f2(&bucket[d * CAP + slot], __int_as_float(s), w);
        }
    } else if (blk < 329) {
        int b = blk - 313;               // 0..15, j-chunk [8b, 8b+8)
        if (tid < 256) {
            int j0 = b * 8;
            float uu = 0.f, vv = 0.f;
            #pragma unroll
            for (int jj = 0; jj < 8; ++jj) {
                float w2 = W2[(j0 + jj) * 256 + tid];   // coalesced, cached
                uu = fmaf(W1[j0 + jj], w2, uu);
                vv = fmaf(b1[j0 + jj], w2, vv);
            }
            st_f(&u_part[b * 256 + tid], uu);
            st_f(&v_part[b * 256 + tid], vv);
        }
    }
    gbar(&bar[0]);

    // ---- phase B: pass1 gather -> sd; pqr partials ----
    if (blk < 313) {
        int gid = blk * 512 + tid;
        int n = gid >> 4;                // node
        int l = gid & 15;                // lane within node group
        if (n < N_NODES) {
            int c = ld_i(&cnt[n]); if (c > CAP) c = CAP;
            float s1 = 0.f, dg = 0.f;
            for (int i = l; i < c; i += 16) {
                float2 e = ld_f2(&bucket[n * CAP + i]);
                s1 = fmaf(e.y, x[__float_as_int(e.x)], s1);  // x: cached, stays hot
                dg += e.y;
            }
            #pragma unroll
            for (int m = 1; m < 16; m <<= 1) {
                s1 += __shfl_xor(s1, m);
                dg += __shfl_xor(dg, m);
            }
            if (l == 0) st_f2(&sd[n], s1, dg);
        }
    } else if (blk < 329) {
        int c = blk - 313;               // 0..15, k-chunk [16c,16c+16)
        if (tid < 16) {
            int kk = c * 16 + tid;
            float uu = 0.f, vv = 0.f;
            #pragma unroll
            for (int b = 0; b < 16; ++b) {
                uu += ld_f(&u_part[b * 256 + kk]);
                vv += ld_f(&v_part[b * 256 + kk]);
            }
            su[tid] = uu; sv[tid] = vv; sb[tid] = b2[kk];
        }
        __syncthreads();
        float pp = 0.f, qq = 0.f, rr = 0.f;
        #pragma unroll
        for (int kk = 0; kk < 16; ++kk) {
            float w3 = W3[(c * 16 + kk) * 512 + tid];   // coalesced, cached
            pp = fmaf(su[kk], w3, pp);
            qq = fmaf(sv[kk], w3, qq);
            rr = fmaf(sb[kk], w3, rr);
        }
        st_f(&p_part[c * 512 + tid], pp);
        st_f(&q_part[c * 512 + tid], qq);
        st_f(&r_part[c * 512 + tid], rr);
    }
    gbar(&bar[1]);

    // ---- phase C: pass2 gather -> t2, Bf; pqr final ----
    if (blk < 313) {
        int gid = blk * 512 + tid;
        int n = gid >> 4;
        int l = gid & 15;
        if (n < N_NODES) {
            int c = ld_i(&cnt[n]); if (c > CAP) c = CAP;
            float tt = 0.f, bb = 0.f;
            for (int i = l; i < c; i += 16) {
                float2 e = ld_f2(&bucket[n * CAP + i]);
                float2 v = ld_f2(&sd[__float_as_int(e.x)]);  // gather (s1, deg)
                tt = fmaf(e.y, v.x, tt);
                bb = fmaf(e.y, v.y, bb);
            }
            #pragma unroll
            for (int m = 1; m < 16; m <<= 1) {
                tt += __shfl_xor(tt, m);
                bb += __shfl_xor(bb, m);
            }
            if (l == 0) { st_f(&t2[n], tt); st_f(&Bf[n], bb); }
        }
    } else if (blk == 329) {
        float pp = 0.f, qq = 0.f, rr = 0.f;
        #pragma unroll
        for (int c2 = 0; c2 < 16; ++c2) {
            pp += ld_f(&p_part[c2 * 512 + tid]);
            qq += ld_f(&q_part[c2 * 512 + tid]);
            rr += ld_f(&r_part[c2 * 512 + tid]);
        }
        st_f(&p[tid], pp); st_f(&q[tid], qq); st_f(&r[tid], rr);
    }
    gbar(&bar[2]);

    // ---- phase D: stage p/q/r to LDS, then A-pass + expansion + sigmoid ----
    {
        const unsigned long long* ps = (const unsigned long long*)p;
        const unsigned long long* qs = (const unsigned long long*)q;
        const unsigned long long* rs = (const unsigned long long*)r;
        if (tid < 256) ((unsigned long long*)sp)[tid] = ld_u64(ps + tid);
        else           ((unsigned long long*)sq)[tid - 256] = ld_u64(qs + (tid - 256));
        if (tid < 256) ((unsigned long long*)sr)[tid] = ld_u64(rs + tid);
    }
    __syncthreads();

    for (int t = blk; t < 625; t += NBLK) {
        int n0 = t * 16;
        if (tid < 256) {
            int nl = tid >> 4;           // local node 0..15
            int l = tid & 15;            // lane within node group
            int n = n0 + nl;
            int c = ld_i(&cnt[n]); if (c > CAP) c = CAP;
            float acc = 0.f;
            for (int i = l; i < c; i += 16) {
                float2 e = ld_f2(&bucket[n * CAP + i]);
                acc = fmaf(e.y, ld_f(&t2[__float_as_int(e.x)]), acc);
            }
            #pragma unroll
            for (int m = 1; m < 16; m <<= 1) acc += __shfl_xor(acc, m);
            if (l == 0) {
                A_l[nl] = acc;
                B_l[nl] = ld_f(&Bf[n]);
                D_l[nl] = ld_f2(&sd[n]).y;   // deg
            }
        }
        __syncthreads();
        #pragma unroll
        for (int h = 0; h < 4; ++h) {
            int idx = h * 512 + tid;     // 0..2047 within tile
            int nl = idx >> 7;           // local node 0..15
            int j = idx & 127;           // float4 column
            float a = A_l[nl], b = B_l[nl], dg = D_l[nl];
            float4 P = ((const float4*)sp)[j];
            float4 Q = ((const float4*)sq)[j];
            float4 R = ((const float4*)sr)[j];
            float4 B3 = ((const float4*)b3)[j];
            float4 o;
            float zx = fmaf(a, P.x, fmaf(b, Q.x, fmaf(dg, R.x, B3.x)));
            float zy = fmaf(a, P.y, fmaf(b, Q.y, fmaf(dg, R.y, B3.y)));
            float zz = fmaf(a, P.z, fmaf(b, Q.z, fmaf(dg, R.z, B3.z)));
            float zw = fmaf(a, P.w, fmaf(b, Q.w, fmaf(dg, R.w, B3.w)));
            o.x = 1.f / (1.f + __expf(-zx));
            o.y = 1.f / (1.f + __expf(-zy));
            o.z = 1.f / (1.f + __expf(-zz));
            o.w = 1.f / (1.f + __expf(-zw));
            ((float4*)out)[(size_t)(n0 + nl) * 128 + j] = o;
        }
        __syncthreads();
    }
}

extern "C" void kernel_launch(void* const* d_in, const int* in_sizes, int n_in,
                              void* d_out, int out_size, void* d_ws, size_t ws_size,
                              hipStream_t stream) {
    const float* x  = (const float*)d_in[0];
    const int*   ei = (const int*)d_in[1];
    const float* ew = (const float*)d_in[2];
    const float* W1 = (const float*)d_in[3];
    const float* b1 = (const float*)d_in[4];
    const float* W2 = (const float*)d_in[5];
    const float* b2 = (const float*)d_in[6];
    const float* W3 = (const float*)d_in[7];
    const float* b3 = (const float*)d_in[8];
    float* out = (float*)d_out;

    float* ws       = (float*)d_ws;
    int*    cnt     = (int*)ws;                    // 10000 ints
    int*    bar     = (int*)(ws + 10240);          // 16 ints
    float2* sd      = (float2*)(ws + 10752);
    float*  t2      = ws + 30752;
    float*  Bf      = ws + 40752;
    float*  p       = ws + 50752;
    float*  q       = ws + 51264;
    float*  r       = ws + 51776;
    float*  u_part  = ws + 52288;
    float*  v_part  = ws + 56384;
    float*  p_part  = ws + 60480;
    float*  q_part  = ws + 68672;
    float*  r_part  = ws + 76864;
    float2* bucket  = (float2*)(ws + 85056);       // 10000 x 64 float2

    const int* src = ei;            // edge_index[0]
    const int* dst = ei + N_EDGES;  // edge_index[1]

    k0_kernel<<<9, 512, 0, stream>>>(cnt, bar);
    mega_kernel<<<NBLK, 512, 0, stream>>>(src, dst, ew, x, cnt, bar,
                                          bucket, sd, t2, Bf,
                                          W1, b1, W2, u_part, v_part,
                                          b2, W3, p_part, q_part, r_part,
                                          p, q, r, b3, out);
}

// Round 7
// 131.062 us; speedup vs baseline: 2.0486x; 1.0187x over previous
//
#include <hip/hip_runtime.h>
#include <math.h>

#define N_NODES 10000
#define N_EDGES 160000
#define CAP 64      // bucket capacity per node (Poisson(16), P(deg>64) ~ 1e-19)
#define NBLK 313    // block n/32 owns nodes [32n, 32n+32); 313*512 >= 160256 edges
#define NPB 32      // nodes per block

// R15: block-owns-nodes + LDS bucket residency.
// R14 post-mortem: fence-free barrier worked (92->65us) but phases re-read the
// 1.28MB bucket uncached 3x, and every gather chain is uncached. Fix: node n is
// owned by block n/32 in ALL phases; phase B copies the node's bucket into LDS
// (16KB/block) while computing pass1; phases C/D consume the LDS copy. Global
// Bf array dropped (LDS-local). cnt/deg cached in LDS after B. NBLK=330->313.
//   D0 (k0):  zero cnt + bar[]  (2 blocks)
//   D1 (mega):
//     phase A: bucket fill (all blocks, 512 edges each) + u,v partials (blk<16)
//     --gbar-- phase B: bucket->LDS + pass1 -> sd=(s1,deg) + p,q,r partials
//     --gbar-- phase C: pass2 (LDS bucket, sd gather) -> t2, lBf; pqr final
//     --gbar-- phase D: A-pass (LDS bucket, t2 gather) + expansion + sigmoid
// Pre-committed tripwire: if mega >= 55us, the mega structure cannot beat the
// R9 multi-dispatch baseline -> revert structure, port LDS-residency there.
//
// Workspace layout (floats):
//   [0      .. 10000)   cnt (int)
//   [10240  .. 10256)   bar (int[16])
//   [10752  .. 30752)   sd  float2(s1,deg)
//   [30752  .. 40752)   t2
//   [40752  .. 41264)   p
//   [41264  .. 41776)   q
//   [41776  .. 42288)   r
//   [42288  .. 46384)   u_part[16][256]
//   [46384  .. 50480)   v_part[16][256]
//   [50480  .. 58672)   p_part[16][512]
//   [58672  .. 66864)   q_part[16][512]
//   [66864  .. 75056)   r_part[16][512]
//   [75056  .. 1355056) bucket[10000][64] float2(src_bits, ew)

// ---- write-through (coherence-point) access helpers -----------------------
__device__ __forceinline__ float2 ld_f2(const float2* p) {
    unsigned long long v = __hip_atomic_load((unsigned long long*)p,
                               __ATOMIC_RELAXED, __HIP_MEMORY_SCOPE_AGENT);
    float2 r;
    r.x = __uint_as_float((unsigned)v);
    r.y = __uint_as_float((unsigned)(v >> 32));
    return r;
}
__device__ __forceinline__ void st_f2(float2* p, float x, float y) {
    unsigned long long v = ((unsigned long long)__float_as_uint(y) << 32)
                         | (unsigned long long)__float_as_uint(x);
    __hip_atomic_store((unsigned long long*)p, v,
                       __ATOMIC_RELAXED, __HIP_MEMORY_SCOPE_AGENT);
}
__device__ __forceinline__ float ld_f(const float* p) {
    return __hip_atomic_load((float*)p, __ATOMIC_RELAXED, __HIP_MEMORY_SCOPE_AGENT);
}
__device__ __forceinline__ void st_f(float* p, float v) {
    __hip_atomic_store(p, v, __ATOMIC_RELAXED, __HIP_MEMORY_SCOPE_AGENT);
}
__device__ __forceinline__ int ld_i(const int* p) {
    return __hip_atomic_load((int*)p, __ATOMIC_RELAXED, __HIP_MEMORY_SCOPE_AGENT);
}
__device__ __forceinline__ unsigned long long ld_u64(const unsigned long long* p) {
    return __hip_atomic_load((unsigned long long*)p,
                             __ATOMIC_RELAXED, __HIP_MEMORY_SCOPE_AGENT);
}

// Fence-free device-wide barrier (R14): all cross-phase data is write-through
// => no cache maintenance; syncthreads drains vmcnt so stores are visible.
__device__ inline void gbar(int* bar) {
    __syncthreads();
    if (threadIdx.x == 0) {
        asm volatile("s_waitcnt vmcnt(0)" ::: "memory");
        __hip_atomic_fetch_add(bar, 1, __ATOMIC_RELAXED, __HIP_MEMORY_SCOPE_AGENT);
        while (__hip_atomic_load(bar, __ATOMIC_RELAXED, __HIP_MEMORY_SCOPE_AGENT) < NBLK)
            __builtin_amdgcn_s_sleep(8);
    }
    __syncthreads();
}

// ---------- D0: zero cnt + bar ---------------------------------------------
__global__ __launch_bounds__(512) void k0_kernel(
        int* __restrict__ cnt, int* __restrict__ bar) {
    int tid = threadIdx.x;
    if (blockIdx.x == 0) {
        int4* c4 = (int4*)cnt;
        for (int g = tid; g < 2500; g += 512)
            c4[g] = make_int4(0, 0, 0, 0);
    } else {
        if (tid < 16) bar[tid] = 0;
    }
}

// ---------- D1: mega-kernel (4 phases, 3 fence-free barriers) --------------
__global__ __launch_bounds__(512, 4) void mega_kernel(
        const int* __restrict__ src, const int* __restrict__ dst,
        const float* __restrict__ ew, const float* __restrict__ x,
        int* __restrict__ cnt, int* __restrict__ bar,
        float2* __restrict__ bucket, float2* __restrict__ sd,
        float* __restrict__ t2,
        const float* __restrict__ W1, const float* __restrict__ b1,
        const float* __restrict__ W2,
        float* __restrict__ u_part, float* __restrict__ v_part,
        const float* __restrict__ b2, const float* __restrict__ W3,
        float* __restrict__ p_part, float* __restrict__ q_part,
        float* __restrict__ r_part,
        float* __restrict__ p, float* __restrict__ q, float* __restrict__ r,
        const float* __restrict__ b3, float* __restrict__ out) {
    int tid = threadIdx.x;
    int blk = blockIdx.x;
    int g = tid >> 4;                    // node group 0..31
    int l = tid & 15;                    // lane within group
    int n = blk * NPB + g;               // owned node (same in all phases)

    __shared__ float2 lbkt[NPB][CAP];    // 16KB: this block's buckets
    __shared__ int   lcnt[NPB];
    __shared__ float ldeg[NPB], lBf[NPB], lA[NPB];
    __shared__ float su[16], sv[16], sb[16];
    __shared__ float sp[512], sq[512], sr[512];

    // ---- phase A: bucket fill (all blocks) + u/v partials (blk<16) ----
    {
        int e = blk * 512 + tid;
        if (e < N_EDGES) {
            int   s = src[e];                    // inputs: normal cached loads
            int   d = dst[e];
            float w = ew[e];
            int slot = atomicAdd(&cnt[d], 1);    // RMW at coherence point
            if (slot < CAP)
                st_f2(&bucket[d * CAP + slot], __int_as_float(s), w);
        }
        if (blk < 16 && tid < 256) {
            int j0 = blk * 8;
            float uu = 0.f, vv = 0.f;
            #pragma unroll
            for (int jj = 0; jj < 8; ++jj) {
                float w2 = W2[(j0 + jj) * 256 + tid];   // coalesced, cached
                uu = fmaf(W1[j0 + jj], w2, uu);
                vv = fmaf(b1[j0 + jj], w2, vv);
            }
            st_f(&u_part[blk * 256 + tid], uu);
            st_f(&v_part[blk * 256 + tid], vv);
        }
    }
    gbar(&bar[0]);

    // ---- phase B: bucket -> LDS + pass1 -> sd; pqr partials (blk<16) ----
    if (n < N_NODES) {
        int c = ld_i(&cnt[n]); if (c > CAP) c = CAP;
        if (l == 0) lcnt[g] = c;
        float s1 = 0.f, dg = 0.f;
        for (int i = l; i < c; i += 16) {
            float2 e = ld_f2(&bucket[n * CAP + i]);  // the ONLY uncached bucket read
            lbkt[g][i] = e;                           // keep resident in LDS
            s1 = fmaf(e.y, x[__float_as_int(e.x)], s1);
            dg += e.y;
        }
        #pragma unroll
        for (int m = 1; m < 16; m <<= 1) {
            s1 += __shfl_xor(s1, m);
            dg += __shfl_xor(dg, m);
        }
        if (l == 0) { st_f2(&sd[n], s1, dg); ldeg[g] = dg; }
    }
    if (blk < 16) {
        int c2 = blk;                    // k-chunk [16c2, 16c2+16)
        if (tid < 16) {
            int kk = c2 * 16 + tid;
            float uu = 0.f, vv = 0.f;
            #pragma unroll
            for (int b = 0; b < 16; ++b) {
                uu += ld_f(&u_part[b * 256 + kk]);
                vv += ld_f(&v_part[b * 256 + kk]);
            }
            su[tid] = uu; sv[tid] = vv; sb[tid] = b2[kk];
        }
        __syncthreads();
        float pp = 0.f, qq = 0.f, rr = 0.f;
        #pragma unroll
        for (int kk = 0; kk < 16; ++kk) {
            float w3 = W3[(c2 * 16 + kk) * 512 + tid];  // coalesced, cached
            pp = fmaf(su[kk], w3, pp);
            qq = fmaf(sv[kk], w3, qq);
            rr = fmaf(sb[kk], w3, rr);
        }
        st_f(&p_part[c2 * 512 + tid], pp);
        st_f(&q_part[c2 * 512 + tid], qq);
        st_f(&r_part[c2 * 512 + tid], rr);
    }
    gbar(&bar[1]);

    // ---- phase C: pass2 (LDS bucket, sd gather) -> t2, lBf; pqr final ----
    if (n < N_NODES) {
        int c = lcnt[g];
        float tt = 0.f, bb = 0.f;
        for (int i = l; i < c; i += 16) {
            float2 e = lbkt[g][i];                      // LDS, free
            float2 v = ld_f2(&sd[__float_as_int(e.x)]); // one uncached gather
            tt = fmaf(e.y, v.x, tt);
            bb = fmaf(e.y, v.y, bb);
        }
        #pragma unroll
        for (int m = 1; m < 16; m <<= 1) {
            tt += __shfl_xor(tt, m);
            bb += __shfl_xor(bb, m);
        }
        if (l == 0) { st_f(&t2[n], tt); lBf[g] = bb; }
    }
    if (blk == 0) {
        float pp = 0.f, qq = 0.f, rr = 0.f;
        #pragma unroll
        for (int c2 = 0; c2 < 16; ++c2) {
            pp += ld_f(&p_part[c2 * 512 + tid]);
            qq += ld_f(&q_part[c2 * 512 + tid]);
            rr += ld_f(&r_part[c2 * 512 + tid]);
        }
        st_f(&p[tid], pp); st_f(&q[tid], qq); st_f(&r[tid], rr);
    }
    gbar(&bar[2]);

    // ---- phase D: stage p/q/r -> LDS; A-pass (LDS bucket); expansion ----
    {
        const unsigned long long* ps = (const unsigned long long*)p;
        const unsigned long long* qs = (const unsigned long long*)q;
        const unsigned long long* rs = (const unsigned long long*)r;
        if (tid < 256) ((unsigned long long*)sp)[tid] = ld_u64(ps + tid);
        else           ((unsigned long long*)sq)[tid - 256] = ld_u64(qs + (tid - 256));
        if (tid < 256) ((unsigned long long*)sr)[tid] = ld_u64(rs + tid);
    }
    if (n < N_NODES) {
        int c = lcnt[g];
        float acc = 0.f;
        for (int i = l; i < c; i += 16) {
            float2 e = lbkt[g][i];                      // LDS, free
            acc = fmaf(e.y, ld_f(&t2[__float_as_int(e.x)]), acc);
        }
        #pragma unroll
        for (int m = 1; m < 16; m <<= 1) acc += __shfl_xor(acc, m);
        if (l == 0) lA[g] = acc;
    }
    __syncthreads();
    #pragma unroll
    for (int h = 0; h < 8; ++h) {
        int idx = h * 512 + tid;         // 0..4095: 32 nodes x 128 float4 cols
        int nl = idx >> 7;               // local node 0..31
        int j = idx & 127;               // float4 column
        int nn = blk * NPB + nl;
        if (nn < N_NODES) {
            float a = lA[nl], bb = lBf[nl], dg = ldeg[nl];
            float4 P = ((const float4*)sp)[j];
            float4 Q = ((const float4*)sq)[j];
            float4 R = ((const float4*)sr)[j];
            float4 B3 = ((const float4*)b3)[j];
            float4 o;
            float zx = fmaf(a, P.x, fmaf(bb, Q.x, fmaf(dg, R.x, B3.x)));
            float zy = fmaf(a, P.y, fmaf(bb, Q.y, fmaf(dg, R.y, B3.y)));
            float zz = fmaf(a, P.z, fmaf(bb, Q.z, fmaf(dg, R.z, B3.z)));
            float zw = fmaf(a, P.w, fmaf(bb, Q.w, fmaf(dg, R.w, B3.w)));
            o.x = 1.f / (1.f + __expf(-zx));
            o.y = 1.f / (1.f + __expf(-zy));
            o.z = 1.f / (1.f + __expf(-zz));
            o.w = 1.f / (1.f + __expf(-zw));
            ((float4*)out)[(size_t)nn * 128 + j] = o;
        }
    }
}

extern "C" void kernel_launch(void* const* d_in, const int* in_sizes, int n_in,
                              void* d_out, int out_size, void* d_ws, size_t ws_size,
                              hipStream_t stream) {
    const float* x  = (const float*)d_in[0];
    const int*   ei = (const int*)d_in[1];
    const float* ew = (const float*)d_in[2];
    const float* W1 = (const float*)d_in[3];
    const float* b1 = (const float*)d_in[4];
    const float* W2 = (const float*)d_in[5];
    const float* b2 = (const float*)d_in[6];
    const float* W3 = (const float*)d_in[7];
    const float* b3 = (const float*)d_in[8];
    float* out = (float*)d_out;

    float* ws       = (float*)d_ws;
    int*    cnt     = (int*)ws;                    // 10000 ints
    int*    bar     = (int*)(ws + 10240);          // 16 ints
    float2* sd      = (float2*)(ws + 10752);
    float*  t2      = ws + 30752;
    float*  p       = ws + 40752;
    float*  q       = ws + 41264;
    float*  r       = ws + 41776;
    float*  u_part  = ws + 42288;
    float*  v_part  = ws + 46384;
    float*  p_part  = ws + 50480;
    float*  q_part  = ws + 58672;
    float*  r_part  = ws + 66864;
    float2* bucket  = (float2*)(ws + 75056);       // 10000 x 64 float2

    const int* src = ei;            // edge_index[0]
    const int* dst = ei + N_EDGES;  // edge_index[1]

    k0_kernel<<<2, 512, 0, stream>>>(cnt, bar);
    mega_kernel<<<NBLK, 512, 0, stream>>>(src, dst, ew, x, cnt, bar,
                                          bucket, sd, t2,
                                          W1, b1, W2, u_part, v_part,
                                          b2, W3, p_part, q_part, r_part,
                                          p, q, r, b3, out);
}

// Round 8
// 126.276 us; speedup vs baseline: 2.1262x; 1.0379x over previous
//
#include <hip/hip_runtime.h>
#include <math.h>

#define N_NODES 10000
#define N_EDGES 160000
#define CAP 64      // bucket capacity per node (Poisson(16), P(deg>64) ~ 1e-19)
#define NBLK 158    // 157 sparse blocks (64 nodes each) + 1 dense block
#define NPB 64      // nodes per block
#define TPB 1024
#define MAGIC 0x5A17C0DE

// R16: ONE user dispatch. Init-free flag barrier. 1 block/CU.
// R15 post-mortem: barriers ~12us each = arrival serialization (313-way
// fetch_add on one line) + arrival skew (wait for slowest of 313 blocks at
// 2/CU) ; boundary cost ~8-10us/dispatch (window arithmetic R12-R15). Fixes:
//  - flag barrier: arrival is an OVERWRITE st(flag[ph][blk]=MAGIC) -> no RMW
//    serialization, no init needed (garbage != MAGIC w.p. 1-2^-32; harness
//    re-poisons ws every iteration, resetting flags between runs -- evidenced
//    by the 268MB fill in every profile). Poll: wave 0 gathers all 158 flags
//    (3/lane) + __all, s_sleep backoff.
//  - 158 blocks x 1024 thr, 1 block/CU (co-resident by construction)
//  - cnt zeroed in-kernel (phase Z); k0 dispatch eliminated
//  - dense chain on otherwise-idle block 157: u,v (LDS) in A; fused one-pass
//    p/q/r = {u,v,b2}@W3 in B. No u/v/p/q/r_part glue arrays.
// Phases: Z(zero cnt) |bar0| A(bucket fill + dense uv) |bar1|
//         B(pass1->sd + dense pqr) |bar2| C(pass2->t2,lBf) |bar3|
//         D(stage pqr->LDS, A-pass, 10000x512 expansion+sigmoid)
// Tripwire (pre-committed): window >= 105us or mega >= 50us -> mega path dead,
// revert to R9 multi-dispatch.
//
// Workspace (floats):
//   [0      .. 10000)   cnt (int)
//   [10240  .. 11264)   flags int[4][256]
//   [11264  .. 31264)   sd  float2(s1,deg)
//   [31264  .. 41264)   t2
//   [41264  .. 41776)   p
//   [41776  .. 42288)   q
//   [42288  .. 42800)   r
//   [43008  .. 1323008) bucket[10000][64] float2(src_bits, ew)

// ---- write-through (coherence-point) access helpers -----------------------
__device__ __forceinline__ float2 ld_f2(const float2* p) {
    unsigned long long v = __hip_atomic_load((unsigned long long*)p,
                               __ATOMIC_RELAXED, __HIP_MEMORY_SCOPE_AGENT);
    float2 r;
    r.x = __uint_as_float((unsigned)v);
    r.y = __uint_as_float((unsigned)(v >> 32));
    return r;
}
__device__ __forceinline__ void st_f2(float2* p, float x, float y) {
    unsigned long long v = ((unsigned long long)__float_as_uint(y) << 32)
                         | (unsigned long long)__float_as_uint(x);
    __hip_atomic_store((unsigned long long*)p, v,
                       __ATOMIC_RELAXED, __HIP_MEMORY_SCOPE_AGENT);
}
__device__ __forceinline__ float ld_f(const float* p) {
    return __hip_atomic_load((float*)p, __ATOMIC_RELAXED, __HIP_MEMORY_SCOPE_AGENT);
}
__device__ __forceinline__ void st_f(float* p, float v) {
    __hip_atomic_store(p, v, __ATOMIC_RELAXED, __HIP_MEMORY_SCOPE_AGENT);
}
__device__ __forceinline__ int ld_i(const int* p) {
    return __hip_atomic_load((int*)p, __ATOMIC_RELAXED, __HIP_MEMORY_SCOPE_AGENT);
}
__device__ __forceinline__ void st_i(int* p, int v) {
    __hip_atomic_store(p, v, __ATOMIC_RELAXED, __HIP_MEMORY_SCOPE_AGENT);
}
__device__ __forceinline__ unsigned long long ld_u64(const unsigned long long* p) {
    return __hip_atomic_load((unsigned long long*)p,
                             __ATOMIC_RELAXED, __HIP_MEMORY_SCOPE_AGENT);
}

// Init-free flag barrier. Data visibility: compiler emits per-wave
// s_waitcnt vmcnt(0) before s_barrier (syncthreads), so every thread's
// write-through stores are at the coherence point before thread 0 publishes
// the MAGIC flag (overwrite store, no RMW). Wave 0 polls all NBLK flags
// (3 per lane) with relaxed loads + __all; no cache maintenance anywhere.
__device__ inline void gbar(int* flags, int ph) {
    __syncthreads();
    int tid = threadIdx.x;
    if (tid == 0) {
        asm volatile("s_waitcnt vmcnt(0)" ::: "memory");
        st_i(&flags[ph * 256 + blockIdx.x], MAGIC);
    }
    if (tid < 64) {
        const int* f = flags + ph * 256;
        int c = tid + 128;
        for (;;) {
            int v0 = ld_i(&f[tid]);
            int v1 = ld_i(&f[tid + 64]);              // tid+64 <= 127 < NBLK
            int v2 = (c < NBLK) ? ld_i(&f[c]) : MAGIC;
            bool ok = (v0 == MAGIC) & (v1 == MAGIC) & (v2 == MAGIC);
            if (__all(ok)) break;
            __builtin_amdgcn_s_sleep(2);
        }
    }
    __syncthreads();
}

// ---------- the single mega-kernel -----------------------------------------
__global__ __launch_bounds__(TPB, 4) void mega_kernel(
        const int* __restrict__ src, const int* __restrict__ dst,
        const float* __restrict__ ew, const float* __restrict__ x,
        int* __restrict__ cnt, int* __restrict__ flags,
        float2* __restrict__ bucket, float2* __restrict__ sd,
        float* __restrict__ t2,
        const float* __restrict__ W1, const float* __restrict__ b1,
        const float* __restrict__ W2, const float* __restrict__ b2,
        const float* __restrict__ W3,
        float* __restrict__ p, float* __restrict__ q, float* __restrict__ r,
        const float* __restrict__ b3, float* __restrict__ out) {
    int tid = threadIdx.x;
    int blk = blockIdx.x;
    int g = tid >> 4;                    // node group 0..63
    int l = tid & 15;                    // lane within group
    int n = blk * NPB + g;               // owned node (sparse blocks only)
    bool sparse = (blk < 157);

    __shared__ float2 lbkt[NPB][CAP];    // 32KB: this block's buckets
    __shared__ int   lcnt[NPB];
    __shared__ float ldeg[NPB], lBf[NPB], lA[NPB];
    __shared__ float su[256], sv[256], sb[256];   // dense block only
    __shared__ float sp[512], sq[512], sr[512];

    // ---- phase Z: zero own cnt (write-through so other blocks' RMWs see it)
    if (sparse && tid < NPB) {
        int nz = blk * NPB + tid;
        if (nz < N_NODES) st_i(&cnt[nz], 0);
    }
    gbar(flags, 0);

    // ---- phase A: bucket fill (blocks 0..156) + dense u,v (block 157) ----
    {
        int e = blk * TPB + tid;
        if (e < N_EDGES) {
            int   s = src[e];                    // inputs: normal cached loads
            int   d = dst[e];
            float w = ew[e];
            int slot = atomicAdd(&cnt[d], 1);    // RMW at coherence point
            if (slot < CAP)
                st_f2(&bucket[d * CAP + slot], __int_as_float(s), w);
        }
        if (blk == 157) {
            if (tid < 256) {
                float uu = 0.f;
                #pragma unroll 8
                for (int j = 0; j < 128; ++j)
                    uu = fmaf(W1[j], W2[j * 256 + tid], uu);   // coalesced
                su[tid] = uu;
            } else if (tid < 512) {
                int k = tid - 256;
                float vv = 0.f;
                #pragma unroll 8
                for (int j = 0; j < 128; ++j)
                    vv = fmaf(b1[j], W2[j * 256 + k], vv);     // L1-hit rows
                sv[k] = vv;
            } else if (tid < 768) {
                sb[tid - 512] = b2[tid - 512];
            }
        }
    }
    gbar(flags, 1);

    // ---- phase B: bucket->LDS + pass1 -> sd (sparse); fused pqr (block 157)
    if (sparse && n < N_NODES) {
        int c = ld_i(&cnt[n]); if (c > CAP) c = CAP;
        if (l == 0) lcnt[g] = c;
        float s1 = 0.f, dg = 0.f;
        for (int i = l; i < c; i += 16) {
            float2 e = ld_f2(&bucket[n * CAP + i]);  // only uncached bucket read
            lbkt[g][i] = e;                           // keep resident in LDS
            s1 = fmaf(e.y, x[__float_as_int(e.x)], s1);   // x: 40KB, cached
            dg += e.y;
        }
        #pragma unroll
        for (int m = 1; m < 16; m <<= 1) {
            s1 += __shfl_xor(s1, m);
            dg += __shfl_xor(dg, m);
        }
        if (l == 0) { st_f2(&sd[n], s1, dg); ldeg[g] = dg; }
    }
    if (blk == 157 && tid < 512) {
        // one pass over W3 (512KB) computing p,q,r together
        float pp = 0.f, qq = 0.f, rr = 0.f;
        #pragma unroll 4
        for (int k = 0; k < 256; ++k) {
            float w3 = W3[k * 512 + tid];            // coalesced, cached
            pp = fmaf(su[k], w3, pp);
            qq = fmaf(sv[k], w3, qq);
            rr = fmaf(sb[k], w3, rr);
        }
        st_f(&p[tid], pp); st_f(&q[tid], qq); st_f(&r[tid], rr);
    }
    gbar(flags, 2);

    // ---- phase C: pass2 (LDS bucket, sd gather) -> t2, lBf ----
    if (sparse && n < N_NODES) {
        int c = lcnt[g];
        float tt = 0.f, bb = 0.f;
        for (int i = l; i < c; i += 16) {
            float2 e = lbkt[g][i];                      // LDS, free
            float2 v = ld_f2(&sd[__float_as_int(e.x)]); // one uncached gather
            tt = fmaf(e.y, v.x, tt);
            bb = fmaf(e.y, v.y, bb);
        }
        #pragma unroll
        for (int m = 1; m < 16; m <<= 1) {
            tt += __shfl_xor(tt, m);
            bb += __shfl_xor(bb, m);
        }
        if (l == 0) { st_f(&t2[n], tt); lBf[g] = bb; }
    }
    gbar(flags, 3);

    // ---- phase D: stage p/q/r -> LDS; A-pass; expansion + sigmoid ----
    if (!sparse) return;                 // blocks 157: done
    {
        const unsigned long long* ps = (const unsigned long long*)p;
        const unsigned long long* qs = (const unsigned long long*)q;
        const unsigned long long* rs = (const unsigned long long*)r;
        if (tid < 256)      ((unsigned long long*)sp)[tid] = ld_u64(ps + tid);
        else if (tid < 512) ((unsigned long long*)sq)[tid - 256] = ld_u64(qs + (tid - 256));
        else if (tid < 768) ((unsigned long long*)sr)[tid - 512] = ld_u64(rs + (tid - 512));
    }
    if (n < N_NODES) {
        int c = lcnt[g];
        float acc = 0.f;
        for (int i = l; i < c; i += 16) {
            float2 e = lbkt[g][i];                      // LDS, free
            acc = fmaf(e.y, ld_f(&t2[__float_as_int(e.x)]), acc);
        }
        #pragma unroll
        for (int m = 1; m < 16; m <<= 1) acc += __shfl_xor(acc, m);
        if (l == 0) lA[g] = acc;
    }
    __syncthreads();
    #pragma unroll
    for (int h = 0; h < 8; ++h) {
        int idx = h * TPB + tid;         // 0..8191: 64 nodes x 128 float4 cols
        int nl = idx >> 7;               // local node 0..63
        int j = idx & 127;               // float4 column
        int nn = blk * NPB + nl;
        if (nn < N_NODES) {
            float a = lA[nl], bb = lBf[nl], dg = ldeg[nl];
            float4 P = ((const float4*)sp)[j];
            float4 Q = ((const float4*)sq)[j];
            float4 R = ((const float4*)sr)[j];
            float4 B3 = ((const float4*)b3)[j];
            float4 o;
            float zx = fmaf(a, P.x, fmaf(bb, Q.x, fmaf(dg, R.x, B3.x)));
            float zy = fmaf(a, P.y, fmaf(bb, Q.y, fmaf(dg, R.y, B3.y)));
            float zz = fmaf(a, P.z, fmaf(bb, Q.z, fmaf(dg, R.z, B3.z)));
            float zw = fmaf(a, P.w, fmaf(bb, Q.w, fmaf(dg, R.w, B3.w)));
            o.x = 1.f / (1.f + __expf(-zx));
            o.y = 1.f / (1.f + __expf(-zy));
            o.z = 1.f / (1.f + __expf(-zz));
            o.w = 1.f / (1.f + __expf(-zw));
            ((float4*)out)[(size_t)nn * 128 + j] = o;
        }
    }
}

extern "C" void kernel_launch(void* const* d_in, const int* in_sizes, int n_in,
                              void* d_out, int out_size, void* d_ws, size_t ws_size,
                              hipStream_t stream) {
    const float* x  = (const float*)d_in[0];
    const int*   ei = (const int*)d_in[1];
    const float* ew = (const float*)d_in[2];
    const float* W1 = (const float*)d_in[3];
    const float* b1 = (const float*)d_in[4];
    const float* W2 = (const float*)d_in[5];
    const float* b2 = (const float*)d_in[6];
    const float* W3 = (const float*)d_in[7];
    const float* b3 = (const float*)d_in[8];
    float* out = (float*)d_out;

    float* ws       = (float*)d_ws;
    int*    cnt     = (int*)ws;                    // 10000 ints
    int*    flags   = (int*)(ws + 10240);          // 4 x 256 ints
    float2* sd      = (float2*)(ws + 11264);
    float*  t2      = ws + 31264;
    float*  p       = ws + 41264;
    float*  q       = ws + 41776;
    float*  r       = ws + 42288;
    float2* bucket  = (float2*)(ws + 43008);       // 10000 x 64 float2

    const int* src = ei;            // edge_index[0]
    const int* dst = ei + N_EDGES;  // edge_index[1]

    mega_kernel<<<NBLK, TPB, 0, stream>>>(src, dst, ew, x, cnt, flags,
                                          bucket, sd, t2,
                                          W1, b1, W2, b2, W3,
                                          p, q, r, b3, out);
}

// Round 9
// 119.292 us; speedup vs baseline: 2.2507x; 1.0585x over previous
//
#include <hip/hip_runtime.h>
#include <math.h>

#define N_NODES 10000
#define N_EDGES 160000
#define CAP 64      // bucket capacity per node (Poisson(16), P(deg>64) ~ 1e-19)

// R17: revert to R9 multi-dispatch (mega/barrier path dead per R12-R16:
// in-kernel device-wide sync costs ~10-12us each on gfx950 regardless of
// implementation -- worse than the ~5us runtime boundary), minus one stage:
// stage-1 (s1,deg materialization) is FUSED into stage-2 by 2-hop bucket
// expansion: t2[n] = sum_e w * s1[src_e], s1 computed on the fly from src's
// bucket (x is 40KB L1-hot, buckets 1.28MB L2-hot; 16x read amplification is
// pipelined independent loads). Deletes one kernel + one boundary + sd array.
//   D0 (k0):  zero cnt (blk 0) + u,v partials (blk 1..16)    [u=W1@W2, v=b1@W2]
//   D1 (k1):  bucket fill (blk 0..312) + p,q,r partials (blk 313..328)
//   D2 (k2f): fused 2-hop -> t2, (Bf,deg) (blk 0..312); p,q,r final (blk 313)
//   D3 (out): A-pass gather + 10000x512 expansion + sigmoid (625 blks)
// Tripwire (pre-committed): window >= 104us -> k2f latency blew up; revert to
// exact R9 5-dispatch next round.
//
// Workspace (floats):
//   [0      .. 10000)   cnt (int)        per-node slot counters
//   [10240  .. 20240)   t2
//   [20240  .. 40240)   bd  float2(Bf,deg)
//   [40240  .. 40752)   p
//   [40752  .. 41264)   q
//   [41264  .. 41776)   r
//   [41776  .. 45872)   u_part[16][256]
//   [45872  .. 49968)   v_part[16][256]
//   [50000  .. 58192)   p_part[16][512]
//   [58192  .. 66384)   q_part[16][512]
//   [66384  .. 74576)   r_part[16][512]
//   [74576  .. 1354576) bucket[10000][64] float2(src_bits, ew)

// ---------- D0: zero cnt + u/v partials ------------------------------------
__global__ __launch_bounds__(512) void k0_kernel(
        int* __restrict__ cnt,
        const float* __restrict__ W1, const float* __restrict__ b1,
        const float* __restrict__ W2,
        float* __restrict__ u_part, float* __restrict__ v_part) {
    int tid = threadIdx.x;
    int blk = blockIdx.x;
    if (blk == 0) {
        for (int g = tid; g < N_NODES / 4; g += 512)
            ((int4*)cnt)[g] = make_int4(0, 0, 0, 0);
    } else {
        int b = blk - 1;                 // 0..15, j-chunk [8b, 8b+8)
        if (tid < 256) {
            int j0 = b * 8;
            float uu = 0.f, vv = 0.f;
            #pragma unroll
            for (int jj = 0; jj < 8; ++jj) {
                float w2 = W2[(j0 + jj) * 256 + tid];   // coalesced
                uu = fmaf(W1[j0 + jj], w2, uu);
                vv = fmaf(b1[j0 + jj], w2, vv);
            }
            u_part[b * 256 + tid] = uu;
            v_part[b * 256 + tid] = vv;
        }
    }
}

// ---------- D1: bucket fill + p/q/r partials (identical to R9) -------------
__global__ __launch_bounds__(512) void k1_kernel(
        const int* __restrict__ src, const int* __restrict__ dst,
        const float* __restrict__ ew,
        int* __restrict__ cnt, float2* __restrict__ bucket,
        const float* __restrict__ u_part, const float* __restrict__ v_part,
        const float* __restrict__ b2, const float* __restrict__ W3,
        float* __restrict__ p_part, float* __restrict__ q_part,
        float* __restrict__ r_part) {
    int tid = threadIdx.x;
    int blk = blockIdx.x;
    if (blk < 313) {
        int e = blk * 512 + tid;
        if (e < N_EDGES) {
            int   s = src[e];
            int   d = dst[e];
            float w = ew[e];
            int slot = atomicAdd(&cnt[d], 1);
            if (slot < CAP)
                bucket[d * CAP + slot] = make_float2(__int_as_float(s), w);
        }
    } else {
        int c = blk - 313;               // 0..15, k-chunk [16c,16c+16)
        __shared__ float su[16], sv[16], sb[16];
        if (tid < 16) {
            int kk = c * 16 + tid;
            float uu = 0.f, vv = 0.f;
            #pragma unroll
            for (int b = 0; b < 16; ++b) {
                uu += u_part[b * 256 + kk];
                vv += v_part[b * 256 + kk];
            }
            su[tid] = uu; sv[tid] = vv; sb[tid] = b2[kk];
        }
        __syncthreads();
        float pp = 0.f, qq = 0.f, rr = 0.f;
        #pragma unroll
        for (int kk = 0; kk < 16; ++kk) {
            float w3 = W3[(c * 16 + kk) * 512 + tid];   // coalesced
            pp = fmaf(su[kk], w3, pp);
            qq = fmaf(sv[kk], w3, qq);
            rr = fmaf(sb[kk], w3, rr);
        }
        p_part[c * 512 + tid] = pp;
        q_part[c * 512 + tid] = qq;
        r_part[c * 512 + tid] = rr;
    }
}

// ---------- D2: fused 2-hop gather -> t2, (Bf,deg); p/q/r final ------------
// blocks 0..312: 32 nodes each, 16 lanes/node. For node n, lane l walks
// n's bucket entries i = l, l+16, ...; for each edge (s,w) it expands s's
// bucket inline:  s1_s = sum w'·x[src'], deg_s = sum w'  (x L1-hot, bucket
// L2-hot, inner loads independent -> pipelined).  t2[n] += w*s1_s,
// Bf[n] += w*deg_s, deg[n] += w.
// block 313: p/q/r 16-way final reduce.
__global__ __launch_bounds__(512) void k2_kernel(
        const int* __restrict__ cnt, const float2* __restrict__ bucket,
        const float* __restrict__ x,
        float* __restrict__ t2, float2* __restrict__ bd,
        const float* __restrict__ p_part, const float* __restrict__ q_part,
        const float* __restrict__ r_part,
        float* __restrict__ p, float* __restrict__ q, float* __restrict__ r) {
    int tid = threadIdx.x;
    int blk = blockIdx.x;
    if (blk < 313) {
        int gid = blk * 512 + tid;
        int n = gid >> 4;                // node
        int l = gid & 15;                // lane within node group
        if (n < N_NODES) {
            int cn = cnt[n]; if (cn > CAP) cn = CAP;
            float t2a = 0.f, bfa = 0.f, dga = 0.f;
            for (int i = l; i < cn; i += 16) {
                float2 e = bucket[n * CAP + i];      // own bucket, coalesced
                int   s = __float_as_int(e.x);
                float w = e.y;
                dga += w;
                int cs = cnt[s]; if (cs > CAP) cs = CAP;
                const float2* bs = &bucket[s * CAP];
                float s1 = 0.f, dgs = 0.f;
                #pragma unroll 4
                for (int j = 0; j < cs; ++j) {       // src's bucket, L2-hot
                    float2 e2 = bs[j];
                    s1 = fmaf(e2.y, x[__float_as_int(e2.x)], s1);
                    dgs += e2.y;
                }
                t2a = fmaf(w, s1, t2a);
                bfa = fmaf(w, dgs, bfa);
            }
            #pragma unroll
            for (int m = 1; m < 16; m <<= 1) {
                t2a += __shfl_xor(t2a, m);
                bfa += __shfl_xor(bfa, m);
                dga += __shfl_xor(dga, m);
            }
            if (l == 0) {
                t2[n] = t2a;
                bd[n] = make_float2(bfa, dga);
            }
        }
    } else {
        float pp = 0.f, qq = 0.f, rr = 0.f;
        #pragma unroll
        for (int c2 = 0; c2 < 16; ++c2) {
            pp += p_part[c2 * 512 + tid];
            qq += q_part[c2 * 512 + tid];
            rr += r_part[c2 * 512 + tid];
        }
        p[tid] = pp; q[tid] = qq; r[tid] = rr;
    }
}

// ---------- D3: output (A-pass prologue + expansion), as R9 ----------------
// 625 blocks x 256 threads; block = 16 nodes x 128 float4 columns.
__global__ __launch_bounds__(256) void output_kernel(
        const int* __restrict__ cnt, const float2* __restrict__ bucket,
        const float* __restrict__ t2, const float2* __restrict__ bd,
        const float* __restrict__ p, const float* __restrict__ q,
        const float* __restrict__ r, const float* __restrict__ b3,
        float* __restrict__ out) {
    int tid = threadIdx.x;
    int n0 = blockIdx.x * 16;
    __shared__ float A_l[16], B_l[16], D_l[16];
    {
        int nl = tid >> 4;               // local node 0..15
        int l = tid & 15;                // lane within node group
        int n = n0 + nl;
        int c = cnt[n]; if (c > CAP) c = CAP;
        float acc = 0.f;
        for (int i = l; i < c; i += 16) {
            float2 e = bucket[n * CAP + i];
            acc = fmaf(e.y, t2[__float_as_int(e.x)], acc);
        }
        #pragma unroll
        for (int m = 1; m < 16; m <<= 1) acc += __shfl_xor(acc, m);
        if (l == 0) {
            float2 v = bd[n];
            A_l[nl] = acc;
            B_l[nl] = v.x;               // Bf
            D_l[nl] = v.y;               // deg
        }
    }
    __syncthreads();
    #pragma unroll
    for (int h = 0; h < 8; ++h) {
        int idx = h * 256 + tid;         // 0..2047 within block
        int nl = idx >> 7;               // local node 0..15
        int j = idx & 127;               // float4 column
        float a = A_l[nl], b = B_l[nl], dg = D_l[nl];
        float4 P = ((const float4*)p)[j];
        float4 Q = ((const float4*)q)[j];
        float4 R = ((const float4*)r)[j];
        float4 B3 = ((const float4*)b3)[j];
        float4 o;
        float zx = fmaf(a, P.x, fmaf(b, Q.x, fmaf(dg, R.x, B3.x)));
        float zy = fmaf(a, P.y, fmaf(b, Q.y, fmaf(dg, R.y, B3.y)));
        float zz = fmaf(a, P.z, fmaf(b, Q.z, fmaf(dg, R.z, B3.z)));
        float zw = fmaf(a, P.w, fmaf(b, Q.w, fmaf(dg, R.w, B3.w)));
        o.x = 1.f / (1.f + __expf(-zx));
        o.y = 1.f / (1.f + __expf(-zy));
        o.z = 1.f / (1.f + __expf(-zz));
        o.w = 1.f / (1.f + __expf(-zw));
        ((float4*)out)[(size_t)(n0 + nl) * 128 + j] = o;
    }
}

extern "C" void kernel_launch(void* const* d_in, const int* in_sizes, int n_in,
                              void* d_out, int out_size, void* d_ws, size_t ws_size,
                              hipStream_t stream) {
    const float* x  = (const float*)d_in[0];
    const int*   ei = (const int*)d_in[1];
    const float* ew = (const float*)d_in[2];
    const float* W1 = (const float*)d_in[3];
    const float* b1 = (const float*)d_in[4];
    const float* W2 = (const float*)d_in[5];
    const float* b2 = (const float*)d_in[6];
    const float* W3 = (const float*)d_in[7];
    const float* b3 = (const float*)d_in[8];
    float* out = (float*)d_out;

    float* ws       = (float*)d_ws;
    int*    cnt     = (int*)ws;                    // 10000 ints
    float*  t2      = ws + 10240;
    float2* bd      = (float2*)(ws + 20240);       // 10000 float2 (Bf,deg)
    float*  p       = ws + 40240;
    float*  q       = ws + 40752;
    float*  r       = ws + 41264;
    float*  u_part  = ws + 41776;
    float*  v_part  = ws + 45872;
    float*  p_part  = ws + 50000;
    float*  q_part  = ws + 58192;
    float*  r_part  = ws + 66384;
    float2* bucket  = (float2*)(ws + 74576);       // 10000 x 64 float2

    const int* src = ei;            // edge_index[0]
    const int* dst = ei + N_EDGES;  // edge_index[1]

    k0_kernel<<<17, 512, 0, stream>>>(cnt, W1, b1, W2, u_part, v_part);
    k1_kernel<<<329, 512, 0, stream>>>(src, dst, ew, cnt, bucket,
                                       u_part, v_part, b2, W3,
                                       p_part, q_part, r_part);
    k2_kernel<<<314, 512, 0, stream>>>(cnt, bucket, x, t2, bd,
                                       p_part, q_part, r_part, p, q, r);
    output_kernel<<<625, 256, 0, stream>>>(cnt, bucket, t2, bd,
                                           p, q, r, b3, out);
}